// Round 8
// baseline (586.199 us; speedup 1.0000x reference)
//
#include <hip/hip_runtime.h>

#define IN_DIM  4096
#define OUT_DIM 1024
#define NN      4096
#define MM      8192
#define NSAMP   10

typedef __bf16 bf16x8 __attribute__((ext_vector_type(8)));
typedef float  fx4    __attribute__((ext_vector_type(4)));

__device__ __forceinline__ ushort f2bf(float f) {
    union { float f; unsigned u; } v; v.f = f;
    unsigned u = v.u;
    return (ushort)((u + 0x7FFFu + ((u >> 16) & 1u)) >> 16);
}
__device__ __forceinline__ float bf2f(ushort u) {
    union { unsigned u; float f; } v; v.u = ((unsigned)u) << 16;
    return v.f;
}

// async global->LDS, 16B per lane; LDS dest = wave-uniform base + lane*16
#define GLDS(g, l) __builtin_amdgcn_global_load_lds(                           \
    (const __attribute__((address_space(1))) unsigned*)(g),                    \
    (__attribute__((address_space(3))) unsigned*)(l), 16, 0, 0)

// ---------------------------------------------------------------------------
// K1: v1[k] = sum_o a1[o]*W[o,k];  v2[k] = sum_o a2[o]*W[o,k]
//     + fused: Wbf = bf16(W)  (W read exactly once here)
// ---------------------------------------------------------------------------
__global__ __launch_bounds__(256) void k_attvec(const float* __restrict__ W,
                                                const float* __restrict__ att,
                                                float* __restrict__ v1,
                                                float* __restrict__ v2,
                                                ushort* __restrict__ Wbf) {
    int k  = blockIdx.x * 256 + threadIdx.x;
    int o0 = blockIdx.y * 16;
    float s1 = 0.f, s2 = 0.f;
#pragma unroll
    for (int o = o0; o < o0 + 16; ++o) {
        float w = W[(size_t)o * IN_DIM + k];
        Wbf[(size_t)o * IN_DIM + k] = f2bf(w);
        s1 += att[o] * w;
        s2 += att[OUT_DIM + o] * w;
    }
    atomicAdd(&v1[k], s1);
    atomicAdd(&v2[k], s2);
}

// ---------------------------------------------------------------------------
// K2: node rows only — nalpha[row] = node_f[row,:] . v1.
// (R8: neigh branch moved into k_gemm; Abf roundtrip eliminated.)
// r7's proven cell: VGPR ~36, occ ~55%, 8 loads in flight per segment.
// ---------------------------------------------------------------------------
__global__ __launch_bounds__(256) void k_rows_node(const float* __restrict__ node_f,
                                                   const float* __restrict__ v1,
                                                   float* __restrict__ nalpha) {
    int row  = blockIdx.x * 4 + (threadIdx.x >> 6);
    int lane = threadIdx.x & 63;
    const float4* xr = reinterpret_cast<const float4*>(node_f + (size_t)row * IN_DIM);
    const float4* vr = reinterpret_cast<const float4*>(v1);
    float s = 0.f;
#pragma unroll 1
    for (int it = 0; it < 4; ++it) {
        int base = lane + it * 256;
        float4 a0 = xr[base], a1 = xr[base + 64], a2 = xr[base + 128], a3 = xr[base + 192];
        float4 b0 = vr[base], b1 = vr[base + 64], b2 = vr[base + 128], b3 = vr[base + 192];
        s += a0.x * b0.x + a0.y * b0.y + a0.z * b0.z + a0.w * b0.w;
        s += a1.x * b1.x + a1.y * b1.y + a1.z * b1.z + a1.w * b1.w;
        s += a2.x * b2.x + a2.y * b2.y + a2.z * b2.z + a2.w * b2.w;
        s += a3.x * b3.x + a3.y * b3.y + a3.z * b3.z + a3.w * b3.w;
    }
#pragma unroll
    for (int off = 32; off > 0; off >>= 1) s += __shfl_down(s, off, 64);
    if (lane == 0) nalpha[row] = s;
}

// ---------------------------------------------------------------------------
// K5 (R8): split-K x2 GEMM, A = neigh_f fp32 staged via ASYNC GLDS (the
// proven mechanism r6 broke), converted to bf16 at fragment-read time.
//   BK=32. LDS: Asf fp32 16KB + Bs bf16 8KB + v2s 8KB = 32KB -> 4 blocks/CU.
//   A layout: rows of 8 x 16B chunks, chunk c stored at c^(r&7) (involution;
//     bank-verified conflict-free for frag reads AND nbeta reads).
//   B layout: rows of 4 x 16B chunks, chunk c at c^(r&3) (residual 2-way
//     conflict = free per m136).
//   A frag: 2x ds_read_b128 fp32 (global chunks 2q,2q+1) -> 8 casts
//     (compiler emits v_cvt_pk_bf16_f32). RNE == f2bf numerics.
//   nbeta fusion: by==0 blocks dot the fp32 LDS tile vs v2s (full fp32
//     accuracy), pair-shfl reduce, atomicAdd. Covers all k via both bz.
// Block mapping: DEFAULT dim3(64,8,2) -> XCD = bx&7, each A panel read by
// ONE XCD (r3/r6 lessons: keep mapping, keep GLDS async).
// Fragment layouts (HW-verified, learn_hip m89):
//   A/B operand: outer = lane&15, k = (lane>>4)*8 + j
//   C/D:         col   = lane&15, row = (lane>>4)*4 + reg
// ---------------------------------------------------------------------------
#define TM 128
#define TN 128
#define BKR 32
#define KSPLIT (IN_DIM / 2)

__global__ __launch_bounds__(256, 4) void k_gemm(const float* __restrict__ Af,
                                                 const ushort* __restrict__ B,
                                                 ushort* __restrict__ P,
                                                 const float* __restrict__ v2,
                                                 float* __restrict__ nbeta) {
    __shared__ __align__(16) float  Asf[TM * BKR];   // 16 KB fp32
    __shared__ __align__(16) ushort Bs[TN * BKR];    // 8 KB bf16
    __shared__ __align__(16) float  v2s[KSPLIT];     // 8 KB
    const int tid  = threadIdx.x;
    const int lane = tid & 63;
    const int wave = tid >> 6;
    const int wm   = (wave >> 1) * 64;
    const int wn   = (wave & 1) * 64;
    const int lrow = lane & 15;
    const int q    = lane >> 4;

    const int bm  = blockIdx.x * TM;
    const int bn  = blockIdx.y * TN;
    const int bz  = blockIdx.z;
    const int kb  = bz * KSPLIT;
    const bool dofuse = (blockIdx.y == 0);

    // A staging: op i covers rows i*32 + (tid>>3); LDS pos chunk tid&7 holds
    // global chunk (tid&7)^(row&7), row&7 == (tid>>3)&7.
    const int srA = tid >> 3;                             // 0..31
    const int scA = (((tid & 7) ^ (srA & 7)) << 2);       // float offset
    const float* gA = Af + (size_t)(bm + srA) * IN_DIM + kb + scA;

    // B staging: op i covers rows i*64 + (tid>>2); chunk tid&3 holds global
    // chunk (tid&3)^(row&3).
    const int srB = tid >> 2;                             // 0..63
    const int scB = (((tid & 3) ^ (srB & 3)) << 3);       // ushort offset
    const ushort* gB = B + (size_t)(bn + srB) * IN_DIM + kb + scB;

    // v2 slice -> LDS (only needed by by==0 blocks)
    if (dofuse) {
#pragma unroll
        for (int i = 0; i < 2; ++i)
            *reinterpret_cast<float4*>(&v2s[tid * 8 + i * 4]) =
                *reinterpret_cast<const float4*>(&v2[kb + tid * 8 + i * 4]);
    }

    const int r2 = tid >> 1;          // nbeta row 0..127
    const int h2 = tid & 1;           // nbeta k-half
    float sdot = 0.f;

    fx4 acc[4][4] = {};

    for (int k0 = 0; k0 < KSPLIT; k0 += BKR) {
#pragma unroll
        for (int i = 0; i < 4; ++i)
            GLDS(gA + k0 + (size_t)i * 32 * IN_DIM,
                 Asf + i * 1024 + wave * 256);
#pragma unroll
        for (int i = 0; i < 2; ++i)
            GLDS(gB + k0 + (size_t)i * 64 * IN_DIM,
                 Bs + i * 2048 + wave * 512);
        __syncthreads();

        bf16x8 af[4], bfr[4];
#pragma unroll
        for (int mi = 0; mi < 4; ++mi) {
            const int row  = wm + mi * 16 + lrow;
            const int base = row * BKR;
            fx4 f0 = *reinterpret_cast<const fx4*>(&Asf[base + (((2 * q)     ^ (lrow & 7)) << 2)]);
            fx4 f1 = *reinterpret_cast<const fx4*>(&Asf[base + (((2 * q + 1) ^ (lrow & 7)) << 2)]);
            bf16x8 t;
            t[0] = (__bf16)f0[0]; t[1] = (__bf16)f0[1]; t[2] = (__bf16)f0[2]; t[3] = (__bf16)f0[3];
            t[4] = (__bf16)f1[0]; t[5] = (__bf16)f1[1]; t[6] = (__bf16)f1[2]; t[7] = (__bf16)f1[3];
            af[mi] = t;
        }
#pragma unroll
        for (int ni = 0; ni < 4; ++ni) {
            const int row = wn + ni * 16 + lrow;
            bfr[ni] = *reinterpret_cast<const bf16x8*>(&Bs[row * BKR + ((q ^ (lrow & 3)) << 3)]);
        }

        if (dofuse) {
#pragma unroll
            for (int c = 0; c < 4; ++c) {
                fx4 a = *reinterpret_cast<const fx4*>(&Asf[r2 * BKR + (((h2 * 4 + c) ^ (r2 & 7)) << 2)]);
                fx4 b = *reinterpret_cast<const fx4*>(&v2s[k0 + h2 * 16 + c * 4]);
                sdot += a[0] * b[0] + a[1] * b[1] + a[2] * b[2] + a[3] * b[3];
            }
        }

#pragma unroll
        for (int mi = 0; mi < 4; ++mi)
#pragma unroll
            for (int ni = 0; ni < 4; ++ni)
                acc[mi][ni] = __builtin_amdgcn_mfma_f32_16x16x32_bf16(af[mi], bfr[ni], acc[mi][ni], 0, 0, 0);
        __syncthreads();
    }

    if (dofuse) {
        sdot += __shfl_xor(sdot, 1, 64);   // pair (2r,2r+1) shares row r2
        if (h2 == 0) atomicAdd(&nbeta[bm + r2], sdot);
    }

    ushort* Pz = P + (size_t)bz * MM * OUT_DIM;
#pragma unroll
    for (int mi = 0; mi < 4; ++mi)
#pragma unroll
        for (int ni = 0; ni < 4; ++ni) {
            int r = bm + wm + mi * 16 + q * 4;
            int c = bn + wn + ni * 16 + lrow;
#pragma unroll
            for (int v = 0; v < 4; ++v)
                Pz[(size_t)(r + v) * OUT_DIM + c] = f2bf(acc[mi][ni][v]);
        }
}

// ---------------------------------------------------------------------------
// K6: parallel prologue — lanes 0..15 of wave 0 compute softmax weights via
// shfl (dup -> weight 0 == reference set semantics).  Gather phase batched:
// 2 batches of 5 samples x 2 halves = 10 independent loads in flight.
// ---------------------------------------------------------------------------
__global__ __launch_bounds__(256) void k_aggregate(const ushort* __restrict__ P,
                                                   const float* __restrict__ nalpha,
                                                   const float* __restrict__ nbeta,
                                                   const int* __restrict__ nidx,
                                                   float* __restrict__ outp) {
    int row = blockIdx.x;
    __shared__ int   s_idx[NSAMP];
    __shared__ float s_w[NSAMP];
    if (threadIdx.x < 16) {
        int t = threadIdx.x;
        int j = (t < NSAMP) ? nidx[row * NSAMP + t] : -1;
        float score = -INFINITY;
        if (t < NSAMP) {
            float x = nalpha[row] + nbeta[j];
            score = x > 0.f ? x : 0.2f * x;
        }
        bool dup = false;
#pragma unroll
        for (int sIdx = 0; sIdx < NSAMP; ++sIdx) {
            int js = __shfl(j, sIdx, 16);
            if (sIdx < t && js == j) dup = true;
        }
        float mx = score;
#pragma unroll
        for (int off = 8; off > 0; off >>= 1) {
            float o = __shfl_xor(mx, off, 16);
            mx = o > mx ? o : mx;
        }
        float e = (t < NSAMP && !dup) ? expf(score - mx) : 0.f;
        float sum = e;
#pragma unroll
        for (int off = 8; off > 0; off >>= 1) sum += __shfl_xor(sum, off, 16);
        if (t < NSAMP) {
            s_idx[t] = j;
            s_w[t]   = e / sum;
        }
    }
    __syncthreads();
    int col = threadIdx.x * 4;
    const ushort* P1 = P + (size_t)MM * OUT_DIM;
    float ax = 0.f, ay = 0.f, az = 0.f, aw = 0.f;
#pragma unroll
    for (int b = 0; b < 2; ++b) {
        ushort4 u0[5], u1[5];
        float   w[5];
#pragma unroll
        for (int t = 0; t < 5; ++t) {
            size_t off = (size_t)s_idx[b * 5 + t] * OUT_DIM + col;
            u0[t] = *reinterpret_cast<const ushort4*>(P + off);
            u1[t] = *reinterpret_cast<const ushort4*>(P1 + off);
            w[t]  = s_w[b * 5 + t];
        }
#pragma unroll
        for (int t = 0; t < 5; ++t) {
            ax += w[t] * (bf2f(u0[t].x) + bf2f(u1[t].x));
            ay += w[t] * (bf2f(u0[t].y) + bf2f(u1[t].y));
            az += w[t] * (bf2f(u0[t].z) + bf2f(u1[t].z));
            aw += w[t] * (bf2f(u0[t].w) + bf2f(u1[t].w));
        }
    }
    float4 o; o.x = ax; o.y = ay; o.z = az; o.w = aw;
    *reinterpret_cast<float4*>(outp + (size_t)row * OUT_DIM + col) = o;
}

// ---------------------------------------------------------------------------
extern "C" void kernel_launch(void* const* d_in, const int* in_sizes, int n_in,
                              void* d_out, int out_size, void* d_ws, size_t ws_size,
                              hipStream_t stream) {
    const float* node_f  = (const float*)d_in[0];  // 4096 x 4096
    const float* neigh_f = (const float*)d_in[1];  // 8192 x 4096
    const float* W       = (const float*)d_in[2];  // 1024 x 4096
    const float* att     = (const float*)d_in[3];  // 2048
    const int*   nidx    = (const int*)d_in[4];    // 4096 x 10
    float* outp = (float*)d_out;                   // 4096 x 1024 fp32

    char* ws = (char*)d_ws;
    ushort* Wbf = (ushort*)ws;                     // 8 MB bf16 W
    ushort* P   = (ushort*)(ws + 8388608);         // 2 x 16 MB bf16 partials
    float*  v1     = (float*)(ws + 41943040);
    float*  v2     = v1 + IN_DIM;
    float*  nbeta  = v2 + IN_DIM;                  // zeroed (gemm atomics)
    float*  nalpha = nbeta + MM;

    // zero v1, v2, nbeta (contiguous): (4096+4096+8192)*4 = 64 KiB
    hipMemsetAsync(v1, 0, (2 * IN_DIM + MM) * sizeof(float), stream);

    k_attvec   <<<dim3(16, 64),   256, 0, stream>>>(W, att, v1, v2, Wbf);
    k_gemm     <<<dim3(64, 8, 2), 256, 0, stream>>>(neigh_f, Wbf, P, v2, nbeta);
    k_rows_node<<<NN / 4,         256, 0, stream>>>(node_f, v1, nalpha);
    k_aggregate<<<NN,             256, 0, stream>>>(P, nalpha, nbeta, nidx, outp);
}

// Round 9
// 370.269 us; speedup vs baseline: 1.5832x; 1.5832x over previous
//
#include <hip/hip_runtime.h>

#define IN_DIM  4096
#define OUT_DIM 1024
#define NN      4096
#define MM      8192
#define NSAMP   10

typedef __bf16 bf16x8 __attribute__((ext_vector_type(8)));
typedef float  fx4    __attribute__((ext_vector_type(4)));
typedef ushort u16x8  __attribute__((ext_vector_type(8)));

__device__ __forceinline__ ushort f2bf(float f) {
    union { float f; unsigned u; } v; v.f = f;
    unsigned u = v.u;
    return (ushort)((u + 0x7FFFu + ((u >> 16) & 1u)) >> 16);
}
__device__ __forceinline__ float bf2f(ushort u) {
    union { unsigned u; float f; } v; v.u = ((unsigned)u) << 16;
    return v.f;
}

// async global->LDS, 16B per lane; LDS dest = wave-uniform base + lane*16
#define GLDS(g, l) __builtin_amdgcn_global_load_lds(                           \
    (const __attribute__((address_space(1))) unsigned*)(g),                    \
    (__attribute__((address_space(3))) unsigned*)(l), 16, 0, 0)

// ---------------------------------------------------------------------------
// K1: v1[k] = sum_o a1[o]*W[o,k];  v2[k] = sum_o a2[o]*W[o,k]
//     + fused: Wbf = bf16(W)  (W read exactly once here)
// ---------------------------------------------------------------------------
__global__ __launch_bounds__(256) void k_attvec(const float* __restrict__ W,
                                                const float* __restrict__ att,
                                                float* __restrict__ v1,
                                                float* __restrict__ v2,
                                                ushort* __restrict__ Wbf) {
    int k  = blockIdx.x * 256 + threadIdx.x;
    int o0 = blockIdx.y * 16;
    float s1 = 0.f, s2 = 0.f;
#pragma unroll
    for (int o = o0; o < o0 + 16; ++o) {
        float w = W[(size_t)o * IN_DIM + k];
        Wbf[(size_t)o * IN_DIM + k] = f2bf(w);
        s1 += att[o] * w;
        s2 += att[OUT_DIM + o] * w;
    }
    atomicAdd(&v1[k], s1);
    atomicAdd(&v2[k], s2);
}

// ---------------------------------------------------------------------------
// K2: one WAVE per row over NN + MM rows (4 rows per 256-thr block).
// r7 proven config: VGPR ~36, occ ~55%, 8 loads in flight per segment.
// (3 occupancy/ILP cells all land at ~92 us -> structural; do not retune.)
// ---------------------------------------------------------------------------
__global__ __launch_bounds__(256) void k_rows(const float* __restrict__ node_f,
                                              const float* __restrict__ neigh_f,
                                              const float* __restrict__ v1,
                                              const float* __restrict__ v2,
                                              float* __restrict__ nalpha,
                                              float* __restrict__ nbeta,
                                              ushort* __restrict__ Abf) {
    int row  = blockIdx.x * 4 + (threadIdx.x >> 6);
    int lane = threadIdx.x & 63;
    float s = 0.f;
    if (row < NN) {
        const float4* xr = reinterpret_cast<const float4*>(node_f + (size_t)row * IN_DIM);
        const float4* vr = reinterpret_cast<const float4*>(v1);
#pragma unroll 1
        for (int it = 0; it < 4; ++it) {
            int base = lane + it * 256;
            float4 a0 = xr[base], a1 = xr[base + 64], a2 = xr[base + 128], a3 = xr[base + 192];
            float4 b0 = vr[base], b1 = vr[base + 64], b2 = vr[base + 128], b3 = vr[base + 192];
            s += a0.x * b0.x + a0.y * b0.y + a0.z * b0.z + a0.w * b0.w;
            s += a1.x * b1.x + a1.y * b1.y + a1.z * b1.z + a1.w * b1.w;
            s += a2.x * b2.x + a2.y * b2.y + a2.z * b2.z + a2.w * b2.w;
            s += a3.x * b3.x + a3.y * b3.y + a3.z * b3.z + a3.w * b3.w;
        }
    } else {
        int j = row - NN;
        const float4* xr = reinterpret_cast<const float4*>(neigh_f + (size_t)j * IN_DIM);
        const float4* vr = reinterpret_cast<const float4*>(v2);
        ushort4* yr = reinterpret_cast<ushort4*>(Abf + (size_t)j * IN_DIM);
#pragma unroll 1
        for (int it = 0; it < 4; ++it) {
            int base = lane + it * 256;
            float4 a0 = xr[base], a1 = xr[base + 64], a2 = xr[base + 128], a3 = xr[base + 192];
            float4 b0 = vr[base], b1 = vr[base + 64], b2 = vr[base + 128], b3 = vr[base + 192];
            s += a0.x * b0.x + a0.y * b0.y + a0.z * b0.z + a0.w * b0.w;
            s += a1.x * b1.x + a1.y * b1.y + a1.z * b1.z + a1.w * b1.w;
            s += a2.x * b2.x + a2.y * b2.y + a2.z * b2.z + a2.w * b2.w;
            s += a3.x * b3.x + a3.y * b3.y + a3.z * b3.z + a3.w * b3.w;
            ushort4 o0, o1, o2, o3;
            o0.x = f2bf(a0.x); o0.y = f2bf(a0.y); o0.z = f2bf(a0.z); o0.w = f2bf(a0.w);
            o1.x = f2bf(a1.x); o1.y = f2bf(a1.y); o1.z = f2bf(a1.z); o1.w = f2bf(a1.w);
            o2.x = f2bf(a2.x); o2.y = f2bf(a2.y); o2.z = f2bf(a2.z); o2.w = f2bf(a2.w);
            o3.x = f2bf(a3.x); o3.y = f2bf(a3.y); o3.z = f2bf(a3.z); o3.w = f2bf(a3.w);
            yr[base]       = o0;
            yr[base + 64]  = o1;
            yr[base + 128] = o2;
            yr[base + 192] = o3;
        }
    }
#pragma unroll
    for (int off = 32; off > 0; off >>= 1) s += __shfl_down(s, off, 64);
    if (lane == 0) {
        if (row < NN) nalpha[row] = s; else nbeta[row - NN] = s;
    }
}

// ---------------------------------------------------------------------------
// K5: split-K x2 GEMM — r5 proven version, verbatim. 128x128 tile, 4 waves
// 2x2 of 64x64, BK=64, GLDS both operands, conflict-free XOR chunk swizzle,
// DEFAULT dim3(64,8,2) mapping (XCD = bx&7 -> each A panel read by ONE XCD).
// Lessons locked in: r3 (don't invert mapping), r6 (don't sync-reg-stage),
// r8 (fp32-A + (256,4) cap -> 330 MB scratch spill; don't).
// Fragment layouts (HW-verified, learn_hip m89):
//   A/B operand: outer = lane&15, k = (lane>>4)*8 + j  (k-step s adds s*32)
//   C/D:         col   = lane&15, row = (lane>>4)*4 + reg
// ---------------------------------------------------------------------------
#define TM 128
#define TN 128
#define BK 64
#define KSPLIT (IN_DIM / 2)

__global__ __launch_bounds__(256, 4) void k_gemm(const ushort* __restrict__ A,
                                                 const ushort* __restrict__ B,
                                                 ushort* __restrict__ P) {
    __shared__ __align__(16) ushort As[TM * BK];   // 16 KB
    __shared__ __align__(16) ushort Bs[TN * BK];   // 16 KB
    const int tid  = threadIdx.x;
    const int lane = tid & 63;
    const int wave = tid >> 6;
    const int wm   = (wave >> 1) * 64;
    const int wn   = (wave & 1) * 64;
    const int lrow = lane & 15;
    const int q    = lane >> 4;

    const int bm  = blockIdx.x * TM;
    const int bn  = blockIdx.y * TN;
    const int bz  = blockIdx.z;
    const int kb  = bz * KSPLIT;

    // staging: wave w covers rows w*32 + (lane>>3) + 8i, chunk lane&7.
    // source chunk pre-swizzled: g = (lane&7) ^ (sr&7), sr&7 == lane>>3.
    const int sr  = wave * 32 + (lane >> 3);
    const int sco = (((lane & 7) ^ (lane >> 3)) << 3);   // ushort offset
    const ushort* gA = A + (size_t)(bm + sr) * IN_DIM + kb + sco;
    const ushort* gB = B + (size_t)(bn + sr) * IN_DIM + kb + sco;
    ushort* lA = As + wave * 2048;
    ushort* lB = Bs + wave * 2048;

    // read-side swizzled chunk offset (ushorts): step s flips bit2 (^32)
    const int c0u = ((q ^ (lrow & 7)) << 3);

    fx4 acc[4][4] = {};

    for (int k0 = 0; k0 < KSPLIT; k0 += BK) {
#pragma unroll
        for (int i = 0; i < 4; ++i)
            GLDS(gA + k0 + (size_t)i * 8 * IN_DIM, lA + i * 512);
#pragma unroll
        for (int i = 0; i < 4; ++i)
            GLDS(gB + k0 + (size_t)i * 8 * IN_DIM, lB + i * 512);
        __syncthreads();

#pragma unroll
        for (int s = 0; s < 2; ++s) {
            const int co = c0u ^ (s << 5);
            bf16x8 af[4], bfr[4];
#pragma unroll
            for (int mi = 0; mi < 4; ++mi)
                af[mi] = *reinterpret_cast<const bf16x8*>(As + (wm + mi * 16 + lrow) * BK + co);
#pragma unroll
            for (int ni = 0; ni < 4; ++ni)
                bfr[ni] = *reinterpret_cast<const bf16x8*>(Bs + (wn + ni * 16 + lrow) * BK + co);
#pragma unroll
            for (int mi = 0; mi < 4; ++mi)
#pragma unroll
                for (int ni = 0; ni < 4; ++ni)
                    acc[mi][ni] = __builtin_amdgcn_mfma_f32_16x16x32_bf16(af[mi], bfr[ni], acc[mi][ni], 0, 0, 0);
        }
        __syncthreads();
    }

    ushort* Pz = P + (size_t)bz * MM * OUT_DIM;
#pragma unroll
    for (int mi = 0; mi < 4; ++mi)
#pragma unroll
        for (int ni = 0; ni < 4; ++ni) {
            int r = bm + wm + mi * 16 + q * 4;
            int c = bn + wn + ni * 16 + lrow;
#pragma unroll
            for (int v = 0; v < 4; ++v)
                Pz[(size_t)(r + v) * OUT_DIM + c] = f2bf(acc[mi][ni][v]);
        }
}

// ---------------------------------------------------------------------------
// K6 (R9): 2 rows per block, 128 threads/row, ushort8 (16B) gathers.
// Mechanism: inferred aggregate ~85 us at only ~2 TB/s effective with 8B
// payload per outstanding load; 16B payload doubles bytes-in-flight per
// load slot at identical traffic and parallelism (2048 blocks).
// Weight phase: lanes 0..15 of wave0 (row0) and wave2 (row1) — per-wave
// shfl-16 dedupe+softmax, proven semantics (dup -> weight 0).
// ---------------------------------------------------------------------------
__global__ __launch_bounds__(256) void k_aggregate(const ushort* __restrict__ P,
                                                   const float* __restrict__ nalpha,
                                                   const float* __restrict__ nbeta,
                                                   const int* __restrict__ nidx,
                                                   float* __restrict__ outp) {
    __shared__ int   s_idx[2][NSAMP];
    __shared__ float s_w[2][NSAMP];
    const int tid  = threadIdx.x;
    const int half = tid >> 7;                    // 0: row0, 1: row1
    const int row  = blockIdx.x * 2 + half;

    if ((tid & 112) == 0) {                       // tid in [0,16) or [128,144)
        int e = tid >> 7;
        int r = blockIdx.x * 2 + e;
        int t = tid & 15;
        int j = (t < NSAMP) ? nidx[r * NSAMP + t] : -1;
        float score = -INFINITY;
        if (t < NSAMP) {
            float x = nalpha[r] + nbeta[j];
            score = x > 0.f ? x : 0.2f * x;
        }
        bool dup = false;
#pragma unroll
        for (int sIdx = 0; sIdx < NSAMP; ++sIdx) {
            int js = __shfl(j, sIdx, 16);
            if (sIdx < t && js == j) dup = true;
        }
        float mx = score;
#pragma unroll
        for (int off = 8; off > 0; off >>= 1) {
            float o = __shfl_xor(mx, off, 16);
            mx = o > mx ? o : mx;
        }
        float e1 = (t < NSAMP && !dup) ? expf(score - mx) : 0.f;
        float sum = e1;
#pragma unroll
        for (int off = 8; off > 0; off >>= 1) sum += __shfl_xor(sum, off, 16);
        if (t < NSAMP) {
            s_idx[e][t] = j;
            s_w[e][t]   = e1 / sum;
        }
    }
    __syncthreads();

    const int col = (tid & 127) * 8;
    const ushort* P1 = P + (size_t)MM * OUT_DIM;
    float a[8] = {};
#pragma unroll
    for (int b = 0; b < 2; ++b) {
        u16x8 u0[5], u1[5];
        float w[5];
#pragma unroll
        for (int t = 0; t < 5; ++t) {
            size_t off = (size_t)s_idx[half][b * 5 + t] * OUT_DIM + col;
            u0[t] = *reinterpret_cast<const u16x8*>(P + off);
            u1[t] = *reinterpret_cast<const u16x8*>(P1 + off);
            w[t]  = s_w[half][b * 5 + t];
        }
#pragma unroll
        for (int t = 0; t < 5; ++t)
#pragma unroll
            for (int i = 0; i < 8; ++i)
                a[i] += w[t] * (bf2f(u0[t][i]) + bf2f(u1[t][i]));
    }
    float* op = outp + (size_t)row * OUT_DIM + col;
    float4 o0, o1;
    o0.x = a[0]; o0.y = a[1]; o0.z = a[2]; o0.w = a[3];
    o1.x = a[4]; o1.y = a[5]; o1.z = a[6]; o1.w = a[7];
    *reinterpret_cast<float4*>(op)     = o0;
    *reinterpret_cast<float4*>(op + 4) = o1;
}

// ---------------------------------------------------------------------------
extern "C" void kernel_launch(void* const* d_in, const int* in_sizes, int n_in,
                              void* d_out, int out_size, void* d_ws, size_t ws_size,
                              hipStream_t stream) {
    const float* node_f  = (const float*)d_in[0];  // 4096 x 4096
    const float* neigh_f = (const float*)d_in[1];  // 8192 x 4096
    const float* W       = (const float*)d_in[2];  // 1024 x 4096
    const float* att     = (const float*)d_in[3];  // 2048
    const int*   nidx    = (const int*)d_in[4];    // 4096 x 10
    float* outp = (float*)d_out;                   // 4096 x 1024 fp32

    char* ws = (char*)d_ws;
    ushort* Abf = (ushort*)ws;                     // 64 MB bf16 A
    ushort* Wbf = (ushort*)(ws + 67108864);        // 8 MB  bf16 W
    ushort* P   = (ushort*)(ws + 75497472);        // 2 x 16 MB bf16 partials
    float*  v1     = (float*)(ws + 109051904);
    float*  v2     = v1 + IN_DIM;
    float*  nalpha = v2 + IN_DIM;
    float*  nbeta  = nalpha + NN;

    hipMemsetAsync(v1, 0, 2 * IN_DIM * sizeof(float), stream);

    k_attvec   <<<dim3(16, 64),   256, 0, stream>>>(W, att, v1, v2, Wbf);
    k_rows     <<<(NN + MM) / 4,  256, 0, stream>>>(node_f, neigh_f, v1, v2, nalpha, nbeta, Abf);
    k_gemm     <<<dim3(64, 8, 2), 256, 0, stream>>>(Abf, Wbf, P);
    k_aggregate<<<NN / 2,         256, 0, stream>>>(P, nalpha, nbeta, nidx, outp);
}

// Round 10
// 368.883 us; speedup vs baseline: 1.5891x; 1.0038x over previous
//
#include <hip/hip_runtime.h>

#define IN_DIM  4096
#define OUT_DIM 1024
#define NN      4096
#define MM      8192
#define NSAMP   10

typedef __bf16 bf16x8 __attribute__((ext_vector_type(8)));
typedef float  fx4    __attribute__((ext_vector_type(4)));
typedef ushort u16x8  __attribute__((ext_vector_type(8)));

__device__ __forceinline__ ushort f2bf(float f) {
    union { float f; unsigned u; } v; v.f = f;
    unsigned u = v.u;
    return (ushort)((u + 0x7FFFu + ((u >> 16) & 1u)) >> 16);
}
__device__ __forceinline__ float bf2f(ushort u) {
    union { unsigned u; float f; } v; v.u = ((unsigned)u) << 16;
    return v.f;
}

// async global->LDS, 16B per lane; LDS dest = wave-uniform base + lane*16
#define GLDS(g, l) __builtin_amdgcn_global_load_lds(                           \
    (const __attribute__((address_space(1))) unsigned*)(g),                    \
    (__attribute__((address_space(3))) unsigned*)(l), 16, 0, 0)

// ---------------------------------------------------------------------------
// K1: v1[k] = sum_o a1[o]*W[o,k];  v2[k] = sum_o a2[o]*W[o,k]
//     + fused: Wbf = bf16(W)  (W read exactly once here)
// ---------------------------------------------------------------------------
__global__ __launch_bounds__(256) void k_attvec(const float* __restrict__ W,
                                                const float* __restrict__ att,
                                                float* __restrict__ v1,
                                                float* __restrict__ v2,
                                                ushort* __restrict__ Wbf) {
    int k  = blockIdx.x * 256 + threadIdx.x;
    int o0 = blockIdx.y * 16;
    float s1 = 0.f, s2 = 0.f;
#pragma unroll
    for (int o = o0; o < o0 + 16; ++o) {
        float w = W[(size_t)o * IN_DIM + k];
        Wbf[(size_t)o * IN_DIM + k] = f2bf(w);
        s1 += att[o] * w;
        s2 += att[OUT_DIM + o] * w;
    }
    atomicAdd(&v1[k], s1);
    atomicAdd(&v2[k], s2);
}

// ---------------------------------------------------------------------------
// K2 (R10): v-vector IN REGISTERS — halves the load-request count.
// Theory: k_rows stuck at 92us across 3 occupancy x ILP cells while m13's
// pure float4 copy does 6.3 TB/s -> limiter is per-CU vmem REQUEST slots,
// and half our requests were L2-resident v-loads occupying slots.
// Structure: block = 16 rows; wave w owns k-window [w*1024, w*1024+1024);
// v-window = 16 VGPR loaded ONCE per block; 8 groups x 2 rows, 8 independent
// row-loads per group; per-row 64-lane shfl reduce -> part[16][4] -> 16
// threads write nalpha/nbeta. Grid: 256 node-blocks + 512 neigh-blocks.
// ---------------------------------------------------------------------------
__global__ __launch_bounds__(256) void k_rows(const float* __restrict__ node_f,
                                              const float* __restrict__ neigh_f,
                                              const float* __restrict__ v1,
                                              const float* __restrict__ v2,
                                              float* __restrict__ nalpha,
                                              float* __restrict__ nbeta,
                                              ushort* __restrict__ Abf) {
    __shared__ float part[16][4];
    const int tid  = threadIdx.x;
    const int lane = tid & 63;
    const int wave = tid >> 6;
    const bool isNode = (blockIdx.x < NN / 16);
    const int row0 = isNode ? blockIdx.x * 16 : (blockIdx.x - NN / 16) * 16;
    const float* X = isNode ? node_f : neigh_f;
    const float* V = isNode ? v1 : v2;

    // v window -> registers (once per block; 16 VGPR)
    const float4* vp = reinterpret_cast<const float4*>(V + wave * 1024);
    const float4 vv0 = vp[lane], vv1 = vp[64 + lane], vv2 = vp[128 + lane], vv3 = vp[192 + lane];

    const float* Xw = X + (size_t)row0 * IN_DIM + wave * 1024;

#pragma unroll 1
    for (int g = 0; g < 8; ++g) {
        const float4* r0p = reinterpret_cast<const float4*>(Xw + (size_t)(2 * g) * IN_DIM);
        const float4* r1p = reinterpret_cast<const float4*>(Xw + (size_t)(2 * g + 1) * IN_DIM);
        float4 a0 = r0p[lane], a1 = r0p[64 + lane], a2 = r0p[128 + lane], a3 = r0p[192 + lane];
        float4 b0 = r1p[lane], b1 = r1p[64 + lane], b2 = r1p[128 + lane], b3 = r1p[192 + lane];

        float s0 = a0.x * vv0.x + a0.y * vv0.y + a0.z * vv0.z + a0.w * vv0.w
                 + a1.x * vv1.x + a1.y * vv1.y + a1.z * vv1.z + a1.w * vv1.w
                 + a2.x * vv2.x + a2.y * vv2.y + a2.z * vv2.z + a2.w * vv2.w
                 + a3.x * vv3.x + a3.y * vv3.y + a3.z * vv3.z + a3.w * vv3.w;
        float s1 = b0.x * vv0.x + b0.y * vv0.y + b0.z * vv0.z + b0.w * vv0.w
                 + b1.x * vv1.x + b1.y * vv1.y + b1.z * vv1.z + b1.w * vv1.w
                 + b2.x * vv2.x + b2.y * vv2.y + b2.z * vv2.z + b2.w * vv2.w
                 + b3.x * vv3.x + b3.y * vv3.y + b3.z * vv3.z + b3.w * vv3.w;

        if (!isNode) {
            ushort* Aw = Abf + (size_t)row0 * IN_DIM + wave * 1024;
            ushort4* y0 = reinterpret_cast<ushort4*>(Aw + (size_t)(2 * g) * IN_DIM);
            ushort4* y1 = reinterpret_cast<ushort4*>(Aw + (size_t)(2 * g + 1) * IN_DIM);
            ushort4 o;
            o.x = f2bf(a0.x); o.y = f2bf(a0.y); o.z = f2bf(a0.z); o.w = f2bf(a0.w); y0[lane]       = o;
            o.x = f2bf(a1.x); o.y = f2bf(a1.y); o.z = f2bf(a1.z); o.w = f2bf(a1.w); y0[64 + lane]  = o;
            o.x = f2bf(a2.x); o.y = f2bf(a2.y); o.z = f2bf(a2.z); o.w = f2bf(a2.w); y0[128 + lane] = o;
            o.x = f2bf(a3.x); o.y = f2bf(a3.y); o.z = f2bf(a3.z); o.w = f2bf(a3.w); y0[192 + lane] = o;
            o.x = f2bf(b0.x); o.y = f2bf(b0.y); o.z = f2bf(b0.z); o.w = f2bf(b0.w); y1[lane]       = o;
            o.x = f2bf(b1.x); o.y = f2bf(b1.y); o.z = f2bf(b1.z); o.w = f2bf(b1.w); y1[64 + lane]  = o;
            o.x = f2bf(b2.x); o.y = f2bf(b2.y); o.z = f2bf(b2.z); o.w = f2bf(b2.w); y1[128 + lane] = o;
            o.x = f2bf(b3.x); o.y = f2bf(b3.y); o.z = f2bf(b3.z); o.w = f2bf(b3.w); y1[192 + lane] = o;
        }

#pragma unroll
        for (int off = 32; off > 0; off >>= 1) {
            s0 += __shfl_down(s0, off, 64);
            s1 += __shfl_down(s1, off, 64);
        }
        if (lane == 0) {
            part[2 * g][wave]     = s0;
            part[2 * g + 1][wave] = s1;
        }
    }
    __syncthreads();
    if (tid < 16) {
        float t = part[tid][0] + part[tid][1] + part[tid][2] + part[tid][3];
        if (isNode) nalpha[row0 + tid] = t;
        else        nbeta[row0 + tid]  = t;
    }
}

// ---------------------------------------------------------------------------
// K5: split-K x2 GEMM — r5 proven version, verbatim. 128x128 tile, 4 waves
// 2x2 of 64x64, BK=64, GLDS both operands, conflict-free XOR chunk swizzle,
// DEFAULT dim3(64,8,2) mapping (XCD = bx&7 -> each A panel read by ONE XCD).
// Lessons locked in: r3 (don't invert mapping), r6 (don't sync-reg-stage),
// r8 (fp32-A + (256,4) cap -> 330 MB scratch spill; don't).
// Fragment layouts (HW-verified, learn_hip m89):
//   A/B operand: outer = lane&15, k = (lane>>4)*8 + j  (k-step s adds s*32)
//   C/D:         col   = lane&15, row = (lane>>4)*4 + reg
// ---------------------------------------------------------------------------
#define TM 128
#define TN 128
#define BK 64
#define KSPLIT (IN_DIM / 2)

__global__ __launch_bounds__(256, 4) void k_gemm(const ushort* __restrict__ A,
                                                 const ushort* __restrict__ B,
                                                 ushort* __restrict__ P) {
    __shared__ __align__(16) ushort As[TM * BK];   // 16 KB
    __shared__ __align__(16) ushort Bs[TN * BK];   // 16 KB
    const int tid  = threadIdx.x;
    const int lane = tid & 63;
    const int wave = tid >> 6;
    const int wm   = (wave >> 1) * 64;
    const int wn   = (wave & 1) * 64;
    const int lrow = lane & 15;
    const int q    = lane >> 4;

    const int bm  = blockIdx.x * TM;
    const int bn  = blockIdx.y * TN;
    const int bz  = blockIdx.z;
    const int kb  = bz * KSPLIT;

    // staging: wave w covers rows w*32 + (lane>>3) + 8i, chunk lane&7.
    // source chunk pre-swizzled: g = (lane&7) ^ (sr&7), sr&7 == lane>>3.
    const int sr  = wave * 32 + (lane >> 3);
    const int sco = (((lane & 7) ^ (lane >> 3)) << 3);   // ushort offset
    const ushort* gA = A + (size_t)(bm + sr) * IN_DIM + kb + sco;
    const ushort* gB = B + (size_t)(bn + sr) * IN_DIM + kb + sco;
    ushort* lA = As + wave * 2048;
    ushort* lB = Bs + wave * 2048;

    // read-side swizzled chunk offset (ushorts): step s flips bit2 (^32)
    const int c0u = ((q ^ (lrow & 7)) << 3);

    fx4 acc[4][4] = {};

    for (int k0 = 0; k0 < KSPLIT; k0 += BK) {
#pragma unroll
        for (int i = 0; i < 4; ++i)
            GLDS(gA + k0 + (size_t)i * 8 * IN_DIM, lA + i * 512);
#pragma unroll
        for (int i = 0; i < 4; ++i)
            GLDS(gB + k0 + (size_t)i * 8 * IN_DIM, lB + i * 512);
        __syncthreads();

#pragma unroll
        for (int s = 0; s < 2; ++s) {
            const int co = c0u ^ (s << 5);
            bf16x8 af[4], bfr[4];
#pragma unroll
            for (int mi = 0; mi < 4; ++mi)
                af[mi] = *reinterpret_cast<const bf16x8*>(As + (wm + mi * 16 + lrow) * BK + co);
#pragma unroll
            for (int ni = 0; ni < 4; ++ni)
                bfr[ni] = *reinterpret_cast<const bf16x8*>(Bs + (wn + ni * 16 + lrow) * BK + co);
#pragma unroll
            for (int mi = 0; mi < 4; ++mi)
#pragma unroll
                for (int ni = 0; ni < 4; ++ni)
                    acc[mi][ni] = __builtin_amdgcn_mfma_f32_16x16x32_bf16(af[mi], bfr[ni], acc[mi][ni], 0, 0, 0);
        }
        __syncthreads();
    }

    ushort* Pz = P + (size_t)bz * MM * OUT_DIM;
#pragma unroll
    for (int mi = 0; mi < 4; ++mi)
#pragma unroll
        for (int ni = 0; ni < 4; ++ni) {
            int r = bm + wm + mi * 16 + q * 4;
            int c = bn + wn + ni * 16 + lrow;
#pragma unroll
            for (int v = 0; v < 4; ++v)
                Pz[(size_t)(r + v) * OUT_DIM + c] = f2bf(acc[mi][ni][v]);
        }
}

// ---------------------------------------------------------------------------
// K6: 2 rows per block, 128 threads/row, ushort8 (16B) gathers (r9; wall-
// neutral vs r7 but fewer instructions — keep). Weight phase: lanes 0..15
// of wave0/wave2, shfl-16 dedupe+softmax (dup -> weight 0).
// ---------------------------------------------------------------------------
__global__ __launch_bounds__(256) void k_aggregate(const ushort* __restrict__ P,
                                                   const float* __restrict__ nalpha,
                                                   const float* __restrict__ nbeta,
                                                   const int* __restrict__ nidx,
                                                   float* __restrict__ outp) {
    __shared__ int   s_idx[2][NSAMP];
    __shared__ float s_w[2][NSAMP];
    const int tid  = threadIdx.x;
    const int half = tid >> 7;                    // 0: row0, 1: row1
    const int row  = blockIdx.x * 2 + half;

    if ((tid & 112) == 0) {                       // tid in [0,16) or [128,144)
        int e = tid >> 7;
        int r = blockIdx.x * 2 + e;
        int t = tid & 15;
        int j = (t < NSAMP) ? nidx[r * NSAMP + t] : -1;
        float score = -INFINITY;
        if (t < NSAMP) {
            float x = nalpha[r] + nbeta[j];
            score = x > 0.f ? x : 0.2f * x;
        }
        bool dup = false;
#pragma unroll
        for (int sIdx = 0; sIdx < NSAMP; ++sIdx) {
            int js = __shfl(j, sIdx, 16);
            if (sIdx < t && js == j) dup = true;
        }
        float mx = score;
#pragma unroll
        for (int off = 8; off > 0; off >>= 1) {
            float o = __shfl_xor(mx, off, 16);
            mx = o > mx ? o : mx;
        }
        float e1 = (t < NSAMP && !dup) ? expf(score - mx) : 0.f;
        float sum = e1;
#pragma unroll
        for (int off = 8; off > 0; off >>= 1) sum += __shfl_xor(sum, off, 16);
        if (t < NSAMP) {
            s_idx[e][t] = j;
            s_w[e][t]   = e1 / sum;
        }
    }
    __syncthreads();

    const int col = (tid & 127) * 8;
    const ushort* P1 = P + (size_t)MM * OUT_DIM;
    float a[8] = {};
#pragma unroll
    for (int b = 0; b < 2; ++b) {
        u16x8 u0[5], u1[5];
        float w[5];
#pragma unroll
        for (int t = 0; t < 5; ++t) {
            size_t off = (size_t)s_idx[half][b * 5 + t] * OUT_DIM + col;
            u0[t] = *reinterpret_cast<const u16x8*>(P + off);
            u1[t] = *reinterpret_cast<const u16x8*>(P1 + off);
            w[t]  = s_w[half][b * 5 + t];
        }
#pragma unroll
        for (int t = 0; t < 5; ++t)
#pragma unroll
            for (int i = 0; i < 8; ++i)
                a[i] += w[t] * (bf2f(u0[t][i]) + bf2f(u1[t][i]));
    }
    float* op = outp + (size_t)row * OUT_DIM + col;
    float4 o0, o1;
    o0.x = a[0]; o0.y = a[1]; o0.z = a[2]; o0.w = a[3];
    o1.x = a[4]; o1.y = a[5]; o1.z = a[6]; o1.w = a[7];
    *reinterpret_cast<float4*>(op)     = o0;
    *reinterpret_cast<float4*>(op + 4) = o1;
}

// ---------------------------------------------------------------------------
extern "C" void kernel_launch(void* const* d_in, const int* in_sizes, int n_in,
                              void* d_out, int out_size, void* d_ws, size_t ws_size,
                              hipStream_t stream) {
    const float* node_f  = (const float*)d_in[0];  // 4096 x 4096
    const float* neigh_f = (const float*)d_in[1];  // 8192 x 4096
    const float* W       = (const float*)d_in[2];  // 1024 x 4096
    const float* att     = (const float*)d_in[3];  // 2048
    const int*   nidx    = (const int*)d_in[4];    // 4096 x 10
    float* outp = (float*)d_out;                   // 4096 x 1024 fp32

    char* ws = (char*)d_ws;
    ushort* Abf = (ushort*)ws;                     // 64 MB bf16 A
    ushort* Wbf = (ushort*)(ws + 67108864);        // 8 MB  bf16 W
    ushort* P   = (ushort*)(ws + 75497472);        // 2 x 16 MB bf16 partials
    float*  v1     = (float*)(ws + 109051904);
    float*  v2     = v1 + IN_DIM;
    float*  nalpha = v2 + IN_DIM;
    float*  nbeta  = nalpha + NN;

    hipMemsetAsync(v1, 0, 2 * IN_DIM * sizeof(float), stream);

    k_attvec   <<<dim3(16, 64),           256, 0, stream>>>(W, att, v1, v2, Wbf);
    k_rows     <<<(NN + MM) / 16,         256, 0, stream>>>(node_f, neigh_f, v1, v2, nalpha, nbeta, Abf);
    k_gemm     <<<dim3(64, 8, 2),         256, 0, stream>>>(Abf, Wbf, P);
    k_aggregate<<<NN / 2,                 256, 0, stream>>>(P, nalpha, nbeta, nidx, outp);
}